// Round 11
// baseline (10617.847 us; speedup 1.0000x reference)
//
#include <hip/hip_runtime.h>
#include <hip/hip_cooperative_groups.h>
#include <math.h>

namespace cg = cooperative_groups;

typedef unsigned int uint32;
typedef __attribute__((ext_vector_type(8))) short bf16x8;
typedef __attribute__((ext_vector_type(4))) float f32x4;

#define BB 4
#define HH 4
#define NSRC 2048
#define NDST 2048
#define IND 256
#define OUTD 64
#define ALPHA 0.2f
#define NB 2048           // value buckets per (b,h)
#define NCH 256           // 8-element chunks per (b,h)

// workspace layout (float offsets)
#define OFF_HDST   0            // 2097152
#define OFF_ASRC   2097152      // 32768
#define OFF_ADST   2129920      // 32768
#define OFF_PK     2162688      // 131072 (float4 {d, w1, w2, idx*64})
#define OFF_C1     2293760      // 262144 (chunk-8 prefix, exclusive)
#define OFF_C2     2555904      // 262144
#define OFF_CZ1    2818048      // 4096
#define OFF_CZ2    2822144      // 4096
#define OFF_T1     2826240      // 1024
#define OFF_TZ1    2827264      // 16
#define OFF_TZ2    2827280      // 16
#define OFF_BST    2827296      // 16*2049 ints
#define OFF_MM     2860080      // 16*2 (lo, inv)
#define OFF_GFH    2860112      // 32768 (Hw^T frags hi, 65536 bf16)
#define OFF_GFL    2892880      // 32768

__device__ __forceinline__ float fast_tanh(float x) {
    float e = __expf(2.f * x);
    return 1.f - 2.f / (e + 1.f);
}

__device__ __forceinline__ uint32 f32_to_bf16_rne(float x) {
    uint32 u = __float_as_uint(x);
    return (u + 0x7fffu + ((u >> 16) & 1u)) >> 16;
}

// split 8 f32 into bf16 hi/lo packed fragments
__device__ __forceinline__ void split8(const float* x, bf16x8& h8, bf16x8& l8) {
    uint32 hw[4], lw[4];
    #pragma unroll
    for (int p = 0; p < 4; ++p) {
        uint32 h0 = f32_to_bf16_rne(x[2 * p]);
        float f0 = __uint_as_float(h0 << 16);
        uint32 l0 = f32_to_bf16_rne(x[2 * p] - f0);
        uint32 h1 = f32_to_bf16_rne(x[2 * p + 1]);
        float f1 = __uint_as_float(h1 << 16);
        uint32 l1 = f32_to_bf16_rne(x[2 * p + 1] - f1);
        hw[p] = h0 | (h1 << 16);
        lw[p] = l0 | (l1 << 16);
    }
    h8 = *(bf16x8*)hw; l8 = *(bf16x8*)lw;
}

#define FSTR 260
#define SMEM_BYTES 45312

// ONE cooperative kernel, three phases separated by grid.sync().
// R10 post-mortem: __launch_bounds__(512,4) capped VGPR at 64 -> scratch
// spills (FETCH 112MB, VALUBusy 6%). Fix: no min-waves bound; compiler
// allocates ~96-130 VGPR -> 2 blocks/CU, no spills.
__global__ __launch_bounds__(512) void fused_all(
        const float* __restrict__ feat_src, const float* __restrict__ feat_dst,
        const float* __restrict__ W, const float* __restrict__ w_src,
        const float* __restrict__ w_dst, const float* __restrict__ Hw,
        const float* __restrict__ Hb, const float* __restrict__ bias,
        float* __restrict__ ws, float* __restrict__ out) {
    cg::grid_group gg = cg::this_grid();
    __shared__ __align__(16) char smem[SMEM_BYTES];
    const int tid = threadIdx.x;
    const int nblk = gridDim.x;
    const int lane = tid & 63, wv = tid >> 6;

    // ================= PHASE A: projection =================
    {
        unsigned short* Ahi = (unsigned short*)smem;            // 16KB
        unsigned short* Alo = (unsigned short*)(smem + 16384);  // 16KB
        float* APART = (float*)(smem + 32768);                  // [2][4][32]
        int hh = wv & 3, half = wv >> 2, nb = half * 2;
        int lr = lane & 15, lq = lane >> 4;
        const float* Wh = W + (size_t)hh * 16384;
        for (int tile = blockIdx.x; tile < 512; tile += nblk) {
            __syncthreads();
            int t = tile & 63, b = (tile >> 6) & 3, s = tile >> 8;
            const float* feat = s ? feat_dst : feat_src;
            const float4* fb = (const float4*)(feat + ((size_t)b * 2048 + t * 32) * IND);
            #pragma unroll
            for (int it = 0; it < 4; ++it) {
                int f4 = it * 512 + tid;
                int row = f4 >> 6, c4 = f4 & 63;
                float4 v = fb[f4];
                float xs[4] = {v.x, v.y, v.z, v.w};
                uint32 hb[4], lb[4];
                #pragma unroll
                for (int j = 0; j < 4; ++j) {
                    hb[j] = f32_to_bf16_rne(xs[j]);
                    float hf = __uint_as_float(hb[j] << 16);
                    lb[j] = f32_to_bf16_rne(xs[j] - hf);
                }
                uint2 hw, lw;
                hw.x = hb[0] | (hb[1] << 16); hw.y = hb[2] | (hb[3] << 16);
                lw.x = lb[0] | (lb[1] << 16); lw.y = lb[2] | (lb[3] << 16);
                int baddr = (row * 512 + c4 * 8) ^ ((row & 7) << 4);
                *(uint2*)((char*)Ahi + baddr) = hw;
                *(uint2*)((char*)Alo + baddr) = lw;
            }
            __syncthreads();
            f32x4 acc[2][2];
            #pragma unroll
            for (int mi = 0; mi < 2; ++mi)
                #pragma unroll
                for (int ni = 0; ni < 2; ++ni) acc[mi][ni] = (f32x4)0.f;
            for (int ks = 0; ks < 8; ++ks) {
                bf16x8 ah[2], al[2], bh8[2], bl8[2];
                #pragma unroll
                for (int mi = 0; mi < 2; ++mi) {
                    int row = mi * 16 + lr;
                    int baddr = (row * 512 + ks * 64 + lq * 16) ^ ((row & 7) << 4);
                    ah[mi] = *(const bf16x8*)((const char*)Ahi + baddr);
                    al[mi] = *(const bf16x8*)((const char*)Alo + baddr);
                }
                int kb = ks * 32 + lq * 8;
                #pragma unroll
                for (int ni = 0; ni < 2; ++ni) {
                    const float* wp = Wh + (size_t)kb * 64 + (nb + ni) * 16 + lr;
                    float xv[8];
                    #pragma unroll
                    for (int j = 0; j < 8; ++j) xv[j] = wp[j * 64];
                    split8(xv, bh8[ni], bl8[ni]);
                }
                #pragma unroll
                for (int mi = 0; mi < 2; ++mi)
                    #pragma unroll
                    for (int ni = 0; ni < 2; ++ni) {
                        acc[mi][ni] = __builtin_amdgcn_mfma_f32_16x16x32_bf16(ah[mi], bh8[ni], acc[mi][ni], 0, 0, 0);
                        acc[mi][ni] = __builtin_amdgcn_mfma_f32_16x16x32_bf16(ah[mi], bl8[ni], acc[mi][ni], 0, 0, 0);
                        acc[mi][ni] = __builtin_amdgcn_mfma_f32_16x16x32_bf16(al[mi], bh8[ni], acc[mi][ni], 0, 0, 0);
                    }
            }
            if (s) {
                float* hd = ws + OFF_HDST + ((size_t)(b * HH + hh) * NDST + t * 32) * OUTD;
                #pragma unroll
                for (int mi = 0; mi < 2; ++mi)
                    #pragma unroll
                    for (int ni = 0; ni < 2; ++ni)
                        #pragma unroll
                        for (int r = 0; r < 4; ++r)
                            hd[(mi * 16 + lq * 4 + r) * 64 + (nb + ni) * 16 + lr] = acc[mi][ni][r];
            }
            const float* wa = (s ? w_dst : w_src) + hh * OUTD;
            float wa_v[2];
            #pragma unroll
            for (int ni = 0; ni < 2; ++ni) wa_v[ni] = wa[(nb + ni) * 16 + lr];
            #pragma unroll
            for (int mi = 0; mi < 2; ++mi)
                #pragma unroll
                for (int r = 0; r < 4; ++r) {
                    float p = fast_tanh(acc[mi][0][r]) * wa_v[0]
                            + fast_tanh(acc[mi][1][r]) * wa_v[1];
                    p += __shfl_xor(p, 1); p += __shfl_xor(p, 2);
                    p += __shfl_xor(p, 4); p += __shfl_xor(p, 8);
                    if (lr == 0) APART[half * 128 + hh * 32 + mi * 16 + lq * 4 + r] = p;
                }
            __syncthreads();
            if (tid < 128) {
                int hh2 = tid >> 5, row = tid & 31;
                float a = APART[hh2 * 32 + row] + APART[128 + hh2 * 32 + row];
                ws[(s ? OFF_ADST : OFF_ASRC) + (b * HH + hh2) * NSRC + t * 32 + row] = a;
            }
        }
    }
    __threadfence();
    gg.sync();

    // ================= PHASE B: bucket + prefix / Hw pack =================
    for (int wb = blockIdx.x; wb < 24; wb += nblk) {
        __syncthreads();
        if (wb >= 16) {
            #pragma unroll
            for (int q = 0; q < 2; ++q) {
                int g = (wb - 16) * 1024 + q * 512 + tid;
                int l = g & 63, ni = (g >> 6) & 3, ks = (g >> 8) & 7, cb = g >> 11;
                int col = cb * 64 + ni * 16 + (l & 15);
                int k0 = ks * 32 + (l >> 4) * 8;
                unsigned short hs[8], lsv[8];
                #pragma unroll
                for (int j = 0; j < 8; ++j) {
                    float w = Hw[(size_t)col * 256 + k0 + j];
                    uint32 hb = f32_to_bf16_rne(w);
                    float hf = __uint_as_float(hb << 16);
                    uint32 lb = f32_to_bf16_rne(w - hf);
                    hs[j] = (unsigned short)hb; lsv[j] = (unsigned short)lb;
                }
                unsigned short* fh = (unsigned short*)(ws + OFF_GFH);
                unsigned short* fl = (unsigned short*)(ws + OFF_GFL);
                int slab = ((cb * 8 + ks) * 4 + ni) * 512 + l * 8;
                #pragma unroll
                for (int j = 0; j < 8; ++j) { fh[slab + j] = hs[j]; fl[slab + j] = lsv[j]; }
            }
            continue;
        }
        int bh = wb;
        int* hist = (int*)smem;                    // 8KB
        float* keysP = (float*)(smem + 8192);      // 8KB
        int* idxP = (int*)(smem + 16384);          // 8KB
        float* w1L = (float*)(smem + 24576);       // 8KB
        float* w2L = (float*)(smem + 32768);       // 8KB
        float* ST1 = (float*)(smem + 40960);       // 2KB
        float* ST2 = (float*)(smem + 43008);       // 2KB
        float* SZ1 = (float*)(smem + 45056);       // 8
        float* SZ2 = (float*)(smem + 45088);       // 8
        float* red = (float*)(smem + 45120);       // 16
        float* loinv = (float*)(smem + 45184);     // 2
        int* wtot = (int*)(smem + 45192);          // 8
        const float* ad = ws + OFF_ADST + bh * NDST;
        float d0 = ad[tid], d1 = ad[tid + 512], d2 = ad[tid + 1024], d3 = ad[tid + 1536];
        float mn = fminf(fminf(d0, d1), fminf(d2, d3));
        float mx = fmaxf(fmaxf(d0, d1), fmaxf(d2, d3));
        #pragma unroll
        for (int off = 32; off; off >>= 1) {
            mn = fminf(mn, __shfl_xor(mn, off));
            mx = fmaxf(mx, __shfl_xor(mx, off));
        }
        if (lane == 0) { red[wv] = mn; red[8 + wv] = mx; }
        hist[tid] = 0; hist[tid + 512] = 0; hist[tid + 1024] = 0; hist[tid + 1536] = 0;
        __syncthreads();
        if (tid == 0) {
            float lo = red[0], hi = red[8];
            #pragma unroll
            for (int i = 1; i < 8; ++i) { lo = fminf(lo, red[i]); hi = fmaxf(hi, red[8 + i]); }
            float wd = hi - lo;
            float inv = (float)NB / (wd + wd * 1e-6f + 1e-30f);
            loinv[0] = lo; loinv[1] = inv;
            ws[OFF_MM + bh * 2] = lo; ws[OFF_MM + bh * 2 + 1] = inv;
        }
        __syncthreads();
        float lo = loinv[0], inv = loinv[1];
        int bk0 = (int)((d0 - lo) * inv); bk0 = bk0 < 0 ? 0 : (bk0 > NB - 1 ? NB - 1 : bk0);
        int bk1 = (int)((d1 - lo) * inv); bk1 = bk1 < 0 ? 0 : (bk1 > NB - 1 ? NB - 1 : bk1);
        int bk2 = (int)((d2 - lo) * inv); bk2 = bk2 < 0 ? 0 : (bk2 > NB - 1 ? NB - 1 : bk2);
        int bk3 = (int)((d3 - lo) * inv); bk3 = bk3 < 0 ? 0 : (bk3 > NB - 1 ? NB - 1 : bk3);
        atomicAdd(&hist[bk0], 1); atomicAdd(&hist[bk1], 1);
        atomicAdd(&hist[bk2], 1); atomicAdd(&hist[bk3], 1);
        __syncthreads();
        int h0 = hist[4 * tid], h1 = hist[4 * tid + 1], h2 = hist[4 * tid + 2], h3 = hist[4 * tid + 3];
        int s = h0 + h1 + h2 + h3, sc = s;
        #pragma unroll
        for (int off = 1; off < 64; off <<= 1) {
            int v = __shfl_up(sc, off);
            if (lane >= off) sc += v;
        }
        if (lane == 63) wtot[wv] = sc;
        __syncthreads();
        if (tid == 0) {
            int r = 0;
            #pragma unroll
            for (int i = 0; i < 8; ++i) { int v = wtot[i]; wtot[i] = r; r += v; }
        }
        __syncthreads();
        int base = wtot[wv] + (sc - s);
        int* bstg = (int*)(ws + OFF_BST) + bh * (NB + 1);
        hist[4 * tid] = base;                    bstg[4 * tid] = base;
        hist[4 * tid + 1] = base + h0;           bstg[4 * tid + 1] = base + h0;
        hist[4 * tid + 2] = base + h0 + h1;      bstg[4 * tid + 2] = base + h0 + h1;
        hist[4 * tid + 3] = base + h0 + h1 + h2; bstg[4 * tid + 3] = base + h0 + h1 + h2;
        if (tid == 0) bstg[NB] = NDST;
        __syncthreads();
        {
            int p = atomicAdd(&hist[bk0], 1);
            keysP[p] = d0; idxP[p] = tid;
            w1L[p] = __expf(d0); w2L[p] = __expf(ALPHA * d0);
            p = atomicAdd(&hist[bk1], 1);
            keysP[p] = d1; idxP[p] = tid + 512;
            w1L[p] = __expf(d1); w2L[p] = __expf(ALPHA * d1);
            p = atomicAdd(&hist[bk2], 1);
            keysP[p] = d2; idxP[p] = tid + 1024;
            w1L[p] = __expf(d2); w2L[p] = __expf(ALPHA * d2);
            p = atomicAdd(&hist[bk3], 1);
            keysP[p] = d3; idxP[p] = tid + 1536;
            w1L[p] = __expf(d3); w2L[p] = __expf(ALPHA * d3);
        }
        __syncthreads();
        {
            float4* pkg = (float4*)(ws + OFF_PK) + (size_t)bh * 2048;
            #pragma unroll
            for (int j = 0; j < 4; ++j) {
                int i = tid + j * 512;
                pkg[i] = make_float4(keysP[i], w1L[i], w2L[i], __int_as_float(idxP[i] * 64));
            }
        }
        // chunk-8 sums: wave wv owns chunks wv*32..+32. PASS 1: raw -> global.
        const float* hd = ws + OFF_HDST + (size_t)bh * NDST * OUTD;
        float* C1g = ws + OFF_C1 + (size_t)bh * NCH * 64;
        float* C2g = ws + OFF_C2 + (size_t)bh * NCH * 64;
        float* CZ1g = ws + OFF_CZ1 + bh * NCH;
        float* CZ2g = ws + OFF_CZ2 + bh * NCH;
        int o = lane;
        float run1 = 0.f, run2 = 0.f, rz1 = 0.f, rz2 = 0.f;
        for (int k = 0; k < 32; ++k) {
            int c = wv * 32 + k;
            float c1 = 0.f, c2 = 0.f, cz1 = 0.f, cz2 = 0.f;
            #pragma unroll
            for (int ii = 0; ii < 8; ++ii) {
                int i = c * 8 + ii;
                int m = idxP[i];
                float w1 = w1L[i], w2 = w2L[i];
                float hv = hd[m * 64 + o];
                c1 += w1 * hv; c2 += w2 * hv; cz1 += w1; cz2 += w2;
            }
            C1g[c * 64 + o] = c1; C2g[c * 64 + o] = c2;
            if (o == 0) { CZ1g[c] = cz1; CZ2g[c] = cz2; }
            run1 += c1; run2 += c2; rz1 += cz1; rz2 += cz2;
        }
        ST1[wv * 64 + o] = run1; ST2[wv * 64 + o] = run2;
        if (lane == 0) { SZ1[wv] = rz1; SZ2[wv] = rz2; }
        __syncthreads();
        float base1 = 0.f, base2 = 0.f, zb1 = 0.f, zb2 = 0.f;
        for (int ss = 0; ss < wv; ++ss) {
            base1 += ST1[ss * 64 + o]; base2 += ST2[ss * 64 + o];
            zb1 += SZ1[ss];            zb2 += SZ2[ss];
        }
        if (wv == 7) {
            ws[OFF_T1 + bh * 64 + o] = base1 + run1;
            if (o == 0) { ws[OFF_TZ1 + bh] = zb1 + rz1; ws[OFF_TZ2 + bh] = zb2 + rz2; }
        }
        // PASS 2: in-place exclusive prefix, batched 8-deep.
        float a1 = base1, a2 = base2, az1 = zb1, az2 = zb2;
        for (int k0 = 0; k0 < 32; k0 += 8) {
            float v1[8], v2[8];
            #pragma unroll
            for (int j = 0; j < 8; ++j) {
                int c = wv * 32 + k0 + j;
                v1[j] = C1g[c * 64 + o]; v2[j] = C2g[c * 64 + o];
            }
            #pragma unroll
            for (int j = 0; j < 8; ++j) {
                int c = wv * 32 + k0 + j;
                C1g[c * 64 + o] = a1; a1 += v1[j];
                C2g[c * 64 + o] = a2; a2 += v2[j];
            }
            if (o == 0) {
                float vz1[8], vz2[8];
                #pragma unroll
                for (int j = 0; j < 8; ++j) {
                    int c = wv * 32 + k0 + j;
                    vz1[j] = CZ1g[c]; vz2[j] = CZ2g[c];
                }
                #pragma unroll
                for (int j = 0; j < 8; ++j) {
                    int c = wv * 32 + k0 + j;
                    CZ1g[c] = az1; az1 += vz1[j];
                    CZ2g[c] = az2; az2 += vz2[j];
                }
            }
        }
    }
    __threadfence();
    gg.sync();

    // ================= PHASE C: attention-output + gate =================
    {
        float* FOUT = (float*)smem;                              // 16.6KB
        unsigned short* Ahi = (unsigned short*)(smem + 16640);   // 8KB
        unsigned short* Alo = (unsigned short*)(smem + 24832);   // 8KB
        int o = lane;
        for (int tile = blockIdx.x; tile < 512; tile += nblk) {
            __syncthreads();
            int b = tile >> 7, brow = (tile & 127) * 16;
            const float4* fb = (const float4*)(feat_src + ((size_t)b * 2048 + brow) * IND);
            #pragma unroll
            for (int it = 0; it < 2; ++it) {
                int f4 = it * 512 + tid;
                int row = f4 >> 6, c4 = f4 & 63;
                float4 v = fb[f4];
                float xs[4] = {v.x, v.y, v.z, v.w};
                uint32 hb[4], lb[4];
                #pragma unroll
                for (int j = 0; j < 4; ++j) {
                    hb[j] = f32_to_bf16_rne(xs[j]);
                    float hf = __uint_as_float(hb[j] << 16);
                    lb[j] = f32_to_bf16_rne(xs[j] - hf);
                }
                uint2 hw, lw;
                hw.x = hb[0] | (hb[1] << 16); hw.y = hb[2] | (hb[3] << 16);
                lw.x = lb[0] | (lb[1] << 16); lw.y = lb[2] | (lb[3] << 16);
                int baddr = (row * 512 + c4 * 8) ^ ((row & 7) << 4);
                *(uint2*)((char*)Ahi + baddr) = hw;
                *(uint2*)((char*)Alo + baddr) = lw;
            }
            {
                int h = wv >> 1;
                int bh = b * 4 + h;
                int nbase = (wv & 1) * 8;
                float T1v = ws[OFF_T1 + bh * 64 + o];
                float tz1 = ws[OFF_TZ1 + bh], tz2 = ws[OFF_TZ2 + bh];
                float blo = ws[OFF_MM + bh * 2], binv = ws[OFF_MM + bh * 2 + 1];
                float biasv = bias[o];
                int r_l = o & 7;
                float t_l = ws[OFF_ASRC + bh * 2048 + brow + nbase + r_l];
                float th_l = -t_l;
                int bk = (int)floorf((th_l - blo) * binv);
                bk = bk < 0 ? 0 : (bk > NB - 1 ? NB - 1 : bk);
                const int* bst = (const int*)(ws + OFF_BST) + bh * (NB + 1);
                int jstart = bst[bk], jend = bst[bk + 1];
                int cch = (jstart + 4) >> 3; if (cch > NCH - 1) cch = NCH - 1;
                int i0c_l = cch << 3;
                int lo2_l = i0c_l < jstart ? i0c_l : jstart;
                int hi2_l = i0c_l > jend ? i0c_l : jend;
                float czp1_l = ws[OFF_CZ1 + bh * NCH + cch];
                float czp2_l = ws[OFF_CZ2 + bh * NCH + cch];
                float c1v[8], c2v[8];
                #pragma unroll
                for (int r = 0; r < 8; ++r) {
                    int cch_r = __builtin_amdgcn_readfirstlane(__shfl(cch, r));
                    c1v[r] = ws[OFF_C1 + ((size_t)bh * NCH + cch_r) * 64 + o];
                    c2v[r] = ws[OFF_C2 + ((size_t)bh * NCH + cch_r) * 64 + o];
                }
                const float4* pk = (const float4*)(ws + OFF_PK) + (size_t)bh * 2048;
                const float* hd = ws + OFF_HDST + (size_t)bh * NDST * OUTD;
                #pragma unroll
                for (int r = 0; r < 8; ++r) {
                    float t_r = __uint_as_float(
                        __builtin_amdgcn_readfirstlane(__float_as_uint(__shfl(t_l, r))));
                    float th = -t_r;
                    int i0c = __builtin_amdgcn_readfirstlane(__shfl(i0c_l, r));
                    int lo2 = __builtin_amdgcn_readfirstlane(__shfl(lo2_l, r));
                    int hi2 = __builtin_amdgcn_readfirstlane(__shfl(hi2_l, r));
                    float p1 = c1v[r], p2 = c2v[r];
                    float zp1 = __shfl(czp1_l, r), zp2 = __shfl(czp2_l, r);
                    for (int i = lo2; i < hi2; i += 8) {
                        float4 q[8];
                        #pragma unroll
                        for (int j = 0; j < 8; ++j) {
                            int ii = i + j < hi2 ? i + j : hi2 - 1;   // uniform
                            q[j] = pk[ii];
                        }
                        float hv[8];
                        #pragma unroll
                        for (int j = 0; j < 8; ++j)
                            hv[j] = hd[__float_as_int(q[j].w) + o];
                        #pragma unroll
                        for (int j = 0; j < 8; ++j) {
                            float sel = (q[j].x <= th ? 1.f : 0.f) - (i + j < i0c ? 1.f : 0.f);
                            sel = (i + j < hi2) ? sel : 0.f;
                            float w1 = q[j].y * sel, w2 = q[j].z * sel;
                            p1 += w1 * hv[j]; p2 += w2 * hv[j]; zp1 += w1; zp2 += w2;
                        }
                    }
                    float et = __expf(t_r), et2 = __expf(ALPHA * t_r);
                    float num = et * (T1v - p1) + et2 * p2;
                    float den = et * (tz1 - zp1) + et2 * zp2;
                    FOUT[(nbase + r) * FSTR + h * 64 + o] = num / den + biasv;
                }
            }
            __syncthreads();
            int lr = lane & 15, lq = lane >> 4;
            int cb = wv >> 1, nb = (wv & 1) * 2;
            const uint4* gfh = (const uint4*)(ws + OFF_GFH);
            const uint4* gfl = (const uint4*)(ws + OFF_GFL);
            f32x4 acc[2];
            acc[0] = (f32x4)0.f; acc[1] = (f32x4)0.f;
            for (int ks = 0; ks < 8; ++ks) {
                bf16x8 ah, al, bh8[2], bl8[2];
                {
                    int row = lr;
                    int baddr = (row * 512 + ks * 64 + lq * 16) ^ ((row & 7) << 4);
                    ah = *(const bf16x8*)((const char*)Ahi + baddr);
                    al = *(const bf16x8*)((const char*)Alo + baddr);
                }
                #pragma unroll
                for (int ni = 0; ni < 2; ++ni) {
                    int idx = ((cb * 8 + ks) * 4 + nb + ni) * 64 + lane;
                    uint4 th_ = gfh[idx], tl_ = gfl[idx];
                    bh8[ni] = *(const bf16x8*)&th_;
                    bl8[ni] = *(const bf16x8*)&tl_;
                }
                #pragma unroll
                for (int ni = 0; ni < 2; ++ni) {
                    acc[ni] = __builtin_amdgcn_mfma_f32_16x16x32_bf16(ah, bh8[ni], acc[ni], 0, 0, 0);
                    acc[ni] = __builtin_amdgcn_mfma_f32_16x16x32_bf16(ah, bl8[ni], acc[ni], 0, 0, 0);
                    acc[ni] = __builtin_amdgcn_mfma_f32_16x16x32_bf16(al, bh8[ni], acc[ni], 0, 0, 0);
                }
            }
            #pragma unroll
            for (int ni = 0; ni < 2; ++ni) {
                int c = cb * 64 + (nb + ni) * 16 + lr;
                float hbv = Hb[c];
                #pragma unroll
                for (int r = 0; r < 4; ++r) {
                    int rl = lq * 4 + r;
                    size_t rg = (size_t)b * 2048 + brow + rl;
                    float x = acc[ni][r] + hbv;
                    float g = 1.f / (1.f + __expf(-x));
                    float fo = FOUT[rl * FSTR + c];
                    float e = fo > 0.f ? fo : expm1f(fo);
                    float fs = feat_src[rg * 256 + c];
                    out[rg * 256 + c] = g * e + (1.f - g) * fs;
                }
            }
        }
    }
}

extern "C" void kernel_launch(void* const* d_in, const int* in_sizes, int n_in,
                              void* d_out, int out_size, void* d_ws, size_t ws_size,
                              hipStream_t stream) {
    const float* feat_src = (const float*)d_in[0];
    const float* feat_dst = (const float*)d_in[1];
    const float* W        = (const float*)d_in[2];
    const float* bias     = (const float*)d_in[3];
    const float* w_src    = (const float*)d_in[4];
    const float* w_dst    = (const float*)d_in[5];
    const float* Hw       = (const float*)d_in[6];
    const float* Hb       = (const float*)d_in[7];
    float* out = (float*)d_out;
    float* ws  = (float*)d_ws;

    int maxb = 0;
    hipOccupancyMaxActiveBlocksPerMultiprocessor(&maxb, fused_all, 512, 0);
    int grid = maxb * 256;
    if (grid > 512) grid = 512;
    if (grid < 1) grid = 1;

    void* args[] = {(void*)&feat_src, (void*)&feat_dst, (void*)&W,
                    (void*)&w_src, (void*)&w_dst, (void*)&Hw,
                    (void*)&Hb, (void*)&bias, (void*)&ws, (void*)&out};
    hipLaunchCooperativeKernel((void*)fused_all, dim3(grid), dim3(512),
                               args, 0, stream);
}

// Round 12
// 66.834 us; speedup vs baseline: 158.8698x; 158.8698x over previous
//
#include <hip/hip_runtime.h>
#include <math.h>

typedef unsigned int uint32;
typedef __attribute__((ext_vector_type(8))) short bf16x8;
typedef __attribute__((ext_vector_type(4))) float f32x4;

#define BB 4
#define HH 4
#define NSRC 2048
#define NDST 2048
#define IND 256
#define OUTD 64
#define ALPHA 0.2f
#define NB 2048           // value buckets per (b,h)
#define NCH 256           // 8-element chunks per (b,h)

// workspace layout (float offsets)
#define OFF_HDST   0            // 2097152
#define OFF_ASRC   2097152      // 32768
#define OFF_ADST   2129920      // 32768
#define OFF_PK     2162688      // 131072 (float4 {d, w1, w2, idx*64})
#define OFF_C1     2293760      // 262144 (chunk-8 prefix, exclusive)
#define OFF_C2     2555904      // 262144
#define OFF_CZ1    2818048      // 4096
#define OFF_CZ2    2822144      // 4096
#define OFF_T1     2826240      // 1024
#define OFF_TZ1    2827264      // 16
#define OFF_TZ2    2827280      // 16
#define OFF_BST    2827296      // 16*2049 ints
#define OFF_MM     2860080      // 16*2 (lo, inv)
#define OFF_GFH    2860112      // 32768 (Hw^T frags hi, 65536 bf16)
#define OFF_GFL    2892880      // 32768

__device__ __forceinline__ float fast_tanh(float x) {
    float e = __expf(2.f * x);
    return 1.f - 2.f / (e + 1.f);
}

__device__ __forceinline__ uint32 f32_to_bf16_rne(float x) {
    uint32 u = __float_as_uint(x);
    return (u + 0x7fffu + ((u >> 16) & 1u)) >> 16;
}

// split 8 f32 into bf16 hi/lo packed fragments
__device__ __forceinline__ void split8(const float* x, bf16x8& h8, bf16x8& l8) {
    uint32 hw[4], lw[4];
    #pragma unroll
    for (int p = 0; p < 4; ++p) {
        uint32 h0 = f32_to_bf16_rne(x[2 * p]);
        float f0 = __uint_as_float(h0 << 16);
        uint32 l0 = f32_to_bf16_rne(x[2 * p] - f0);
        uint32 h1 = f32_to_bf16_rne(x[2 * p + 1]);
        float f1 = __uint_as_float(h1 << 16);
        uint32 l1 = f32_to_bf16_rne(x[2 * p + 1] - f1);
        hw[p] = h0 | (h1 << 16);
        lw[p] = l0 | (l1 << 16);
    }
    h8 = *(bf16x8*)hw; l8 = *(bf16x8*)lw;
}

// K1: projection via MFMA, split-bf16 3-pass. Block: 32 rows x 4 heads
// (wave w = head w). W fragments gathered per-lane from global (L2-resident).
// grid: s(2)*b(4)*t(64) = 512 blocks, 256 threads.
__global__ __launch_bounds__(256) void k1_mfma(const float* __restrict__ feat_src,
                                               const float* __restrict__ feat_dst,
                                               const float* __restrict__ W,
                                               const float* __restrict__ w_src,
                                               const float* __restrict__ w_dst,
                                               float* __restrict__ ws) {
    __shared__ __align__(16) unsigned short Ahi[32 * 256];   // 16KB
    __shared__ __align__(16) unsigned short Alo[32 * 256];   // 16KB
    int bid = blockIdx.x;
    int t = bid & 63, b = (bid >> 6) & 3, s = bid >> 8;
    int tid = threadIdx.x;
    const float* feat = s ? feat_dst : feat_src;
    const float4* fb = (const float4*)(feat + ((size_t)b * 2048 + t * 32) * IND);
    // stage feat tile -> bf16 hi/lo LDS, XOR swizzle (byte ^= (row&7)<<4)
    #pragma unroll
    for (int it = 0; it < 8; ++it) {
        int f4 = it * 256 + tid;
        int row = f4 >> 6, c4 = f4 & 63;
        float4 v = fb[f4];
        float xs[4] = {v.x, v.y, v.z, v.w};
        uint32 hb[4], lb[4];
        #pragma unroll
        for (int j = 0; j < 4; ++j) {
            hb[j] = f32_to_bf16_rne(xs[j]);
            float hf = __uint_as_float(hb[j] << 16);
            lb[j] = f32_to_bf16_rne(xs[j] - hf);
        }
        uint2 hw, lw;
        hw.x = hb[0] | (hb[1] << 16); hw.y = hb[2] | (hb[3] << 16);
        lw.x = lb[0] | (lb[1] << 16); lw.y = lb[2] | (lb[3] << 16);
        int baddr = (row * 512 + c4 * 8) ^ ((row & 7) << 4);
        *(uint2*)((char*)Ahi + baddr) = hw;
        *(uint2*)((char*)Alo + baddr) = lw;
    }
    __syncthreads();
    int w = tid >> 6, l = tid & 63;
    int lr = l & 15, lq = l >> 4;
    const float* Wh = W + (size_t)w * 16384;
    f32x4 acc[2][4];
    #pragma unroll
    for (int mi = 0; mi < 2; ++mi)
        #pragma unroll
        for (int ni = 0; ni < 4; ++ni) acc[mi][ni] = (f32x4)0.f;
    for (int ks = 0; ks < 8; ++ks) {
        bf16x8 ah[2], al[2], bh8[4], bl8[4];
        #pragma unroll
        for (int mi = 0; mi < 2; ++mi) {
            int row = mi * 16 + lr;
            int baddr = (row * 512 + ks * 64 + lq * 16) ^ ((row & 7) << 4);
            ah[mi] = *(const bf16x8*)((const char*)Ahi + baddr);
            al[mi] = *(const bf16x8*)((const char*)Alo + baddr);
        }
        int kb = ks * 32 + lq * 8;
        #pragma unroll
        for (int ni = 0; ni < 4; ++ni) {
            const float* wp = Wh + (size_t)kb * 64 + ni * 16 + lr;
            float xv[8];
            #pragma unroll
            for (int j = 0; j < 8; ++j) xv[j] = wp[j * 64];
            split8(xv, bh8[ni], bl8[ni]);
        }
        #pragma unroll
        for (int mi = 0; mi < 2; ++mi)
            #pragma unroll
            for (int ni = 0; ni < 4; ++ni) {
                acc[mi][ni] = __builtin_amdgcn_mfma_f32_16x16x32_bf16(ah[mi], bh8[ni], acc[mi][ni], 0, 0, 0);
                acc[mi][ni] = __builtin_amdgcn_mfma_f32_16x16x32_bf16(ah[mi], bl8[ni], acc[mi][ni], 0, 0, 0);
                acc[mi][ni] = __builtin_amdgcn_mfma_f32_16x16x32_bf16(al[mi], bh8[ni], acc[mi][ni], 0, 0, 0);
            }
    }
    if (s) {
        float* hd = ws + OFF_HDST + ((size_t)(b * HH + w) * NDST + t * 32) * OUTD;
        #pragma unroll
        for (int mi = 0; mi < 2; ++mi)
            #pragma unroll
            for (int ni = 0; ni < 4; ++ni)
                #pragma unroll
                for (int r = 0; r < 4; ++r)
                    hd[(mi * 16 + lq * 4 + r) * 64 + ni * 16 + lr] = acc[mi][ni][r];
    }
    const float* wa = (s ? w_dst : w_src) + w * OUTD;
    float wa_v[4];
    #pragma unroll
    for (int ni = 0; ni < 4; ++ni) wa_v[ni] = wa[ni * 16 + lr];
    float* ap = ws + (s ? OFF_ADST : OFF_ASRC) + (b * HH + w) * NSRC + t * 32;
    #pragma unroll
    for (int mi = 0; mi < 2; ++mi)
        #pragma unroll
        for (int r = 0; r < 4; ++r) {
            float p = 0.f;
            #pragma unroll
            for (int ni = 0; ni < 4; ++ni) p += fast_tanh(acc[mi][ni][r]) * wa_v[ni];
            p += __shfl_xor(p, 1); p += __shfl_xor(p, 2);
            p += __shfl_xor(p, 4); p += __shfl_xor(p, 8);
            if (lr == 0) ap[mi * 16 + lq * 4 + r] = p;
        }
}

// KMID: blocks 0..15: per (b,h) bucket permutation + chunk-8 sums +
// two-pass register-light prefix (no VGPR arrays -> no scratch spill at
// 1024thr/64-VGPR cap). Blocks 16..23: pack Hw^T into MFMA B-frag order.
// grid: 24 blocks, 1024 threads.
__global__ __launch_bounds__(1024) void kmid(const float* __restrict__ Hw,
                                             float* __restrict__ ws) {
    if (blockIdx.x >= 16) {
        // Hw^T fragment packing: 8192 lane-slots, one per thread.
        int g = (blockIdx.x - 16) * 1024 + threadIdx.x;   // 0..8191
        int l = g & 63, ni = (g >> 6) & 3, ks = (g >> 8) & 7, cb = g >> 11;
        int col = cb * 64 + ni * 16 + (l & 15);
        int k0 = ks * 32 + (l >> 4) * 8;
        unsigned short hs[8], lsv[8];
        #pragma unroll
        for (int j = 0; j < 8; ++j) {
            float w = Hw[(size_t)col * 256 + k0 + j];
            uint32 hb = f32_to_bf16_rne(w);
            float hf = __uint_as_float(hb << 16);
            uint32 lb = f32_to_bf16_rne(w - hf);
            hs[j] = (unsigned short)hb; lsv[j] = (unsigned short)lb;
        }
        unsigned short* fh = (unsigned short*)(ws + OFF_GFH);
        unsigned short* fl = (unsigned short*)(ws + OFF_GFL);
        int slab = ((cb * 8 + ks) * 4 + ni) * 512 + l * 8;
        #pragma unroll
        for (int j = 0; j < 8; ++j) { fh[slab + j] = hs[j]; fl[slab + j] = lsv[j]; }
        return;
    }
    __shared__ int   hist[2048];      // counts -> reused as scatter cursors
    __shared__ float keysP[2048];
    __shared__ int   idxP[2048];
    __shared__ float w1L[2048];
    __shared__ float w2L[2048];
    __shared__ float ST1[16 * 64], ST2[16 * 64];
    __shared__ float SZ1[16], SZ2[16];
    __shared__ float red[32];
    __shared__ float loinv[2];
    __shared__ int wtot[16];
    int bh = blockIdx.x, tid = threadIdx.x;
    int lane = tid & 63, wv = tid >> 6;
    const float* ad = ws + OFF_ADST + bh * NDST;
    float d0 = ad[tid], d1 = ad[tid + 1024];
    float mn = fminf(d0, d1), mx = fmaxf(d0, d1);
    #pragma unroll
    for (int off = 32; off; off >>= 1) {
        mn = fminf(mn, __shfl_xor(mn, off));
        mx = fmaxf(mx, __shfl_xor(mx, off));
    }
    if (lane == 0) { red[wv] = mn; red[16 + wv] = mx; }
    hist[tid] = 0; hist[tid + 1024] = 0;
    __syncthreads();
    if (tid == 0) {
        float lo = red[0], hi = red[16];
        #pragma unroll
        for (int i = 1; i < 16; ++i) { lo = fminf(lo, red[i]); hi = fmaxf(hi, red[16 + i]); }
        float wd = hi - lo;
        float inv = (float)NB / (wd + wd * 1e-6f + 1e-30f);
        loinv[0] = lo; loinv[1] = inv;
        ws[OFF_MM + bh * 2] = lo; ws[OFF_MM + bh * 2 + 1] = inv;
    }
    __syncthreads();
    float lo = loinv[0], inv = loinv[1];
    int b0 = (int)((d0 - lo) * inv); b0 = b0 < 0 ? 0 : (b0 > NB - 1 ? NB - 1 : b0);
    int b1 = (int)((d1 - lo) * inv); b1 = b1 < 0 ? 0 : (b1 > NB - 1 ? NB - 1 : b1);
    atomicAdd(&hist[b0], 1);
    atomicAdd(&hist[b1], 1);
    __syncthreads();
    int h0 = hist[2 * tid], h1 = hist[2 * tid + 1];
    int s = h0 + h1, sc = s;
    #pragma unroll
    for (int off = 1; off < 64; off <<= 1) {
        int v = __shfl_up(sc, off);
        if (lane >= off) sc += v;
    }
    if (lane == 63) wtot[wv] = sc;
    __syncthreads();
    if (tid == 0) {
        int r = 0;
        #pragma unroll
        for (int i = 0; i < 16; ++i) { int v = wtot[i]; wtot[i] = r; r += v; }
    }
    __syncthreads();
    int base = wtot[wv] + (sc - s);
    int* bstg = (int*)(ws + OFF_BST) + bh * (NB + 1);
    hist[2 * tid] = base;
    hist[2 * tid + 1] = base + h0;
    bstg[2 * tid] = base;
    bstg[2 * tid + 1] = base + h0;
    if (tid == 0) bstg[NB] = NDST;
    __syncthreads();
    int p0 = atomicAdd(&hist[b0], 1);
    keysP[p0] = d0; idxP[p0] = tid;
    w1L[p0] = __expf(d0); w2L[p0] = __expf(ALPHA * d0);
    int p1 = atomicAdd(&hist[b1], 1);
    keysP[p1] = d1; idxP[p1] = tid + 1024;
    w1L[p1] = __expf(d1); w2L[p1] = __expf(ALPHA * d1);
    __syncthreads();
    // packed PK dump: {d, w1, w2, idx*64 (int bits)}
    {
        float4* pkg = (float4*)(ws + OFF_PK) + (size_t)bh * 2048;
        pkg[tid] = make_float4(keysP[tid], w1L[tid], w2L[tid],
                               __int_as_float(idxP[tid] * 64));
        pkg[tid + 1024] = make_float4(keysP[tid + 1024], w1L[tid + 1024], w2L[tid + 1024],
                                      __int_as_float(idxP[tid + 1024] * 64));
    }
    // chunk-8 sums: wave wv owns chunks wv*16..wv*16+16, lane = o.
    // PASS 1: raw sums -> global, only scalar running totals in regs.
    const float* hd = ws + OFF_HDST + (size_t)bh * NDST * OUTD;
    float* C1g = ws + OFF_C1 + (size_t)bh * NCH * 64;
    float* C2g = ws + OFF_C2 + (size_t)bh * NCH * 64;
    float* CZ1g = ws + OFF_CZ1 + bh * NCH;
    float* CZ2g = ws + OFF_CZ2 + bh * NCH;
    int o = lane;
    float run1 = 0.f, run2 = 0.f, rz1 = 0.f, rz2 = 0.f;
    for (int k = 0; k < 16; ++k) {
        int c = wv * 16 + k;
        float c1 = 0.f, c2 = 0.f, cz1 = 0.f, cz2 = 0.f;
        #pragma unroll
        for (int ii = 0; ii < 8; ++ii) {
            int i = c * 8 + ii;
            int m = idxP[i];
            float w1 = w1L[i], w2 = w2L[i];
            float hv = hd[m * 64 + o];
            c1 += w1 * hv; c2 += w2 * hv; cz1 += w1; cz2 += w2;
        }
        C1g[c * 64 + o] = c1; C2g[c * 64 + o] = c2;         // raw
        if (o == 0) { CZ1g[c] = cz1; CZ2g[c] = cz2; }       // raw
        run1 += c1; run2 += c2; rz1 += cz1; rz2 += cz2;
    }
    ST1[wv * 64 + o] = run1; ST2[wv * 64 + o] = run2;
    if (lane == 0) { SZ1[wv] = rz1; SZ2[wv] = rz2; }
    __syncthreads();
    float base1 = 0.f, base2 = 0.f, zb1 = 0.f, zb2 = 0.f;
    for (int ss = 0; ss < wv; ++ss) {
        base1 += ST1[ss * 64 + o]; base2 += ST2[ss * 64 + o];
        zb1 += SZ1[ss];            zb2 += SZ2[ss];
    }
    if (wv == 15) {
        ws[OFF_T1 + bh * 64 + o] = base1 + run1;
        if (o == 0) { ws[OFF_TZ1 + bh] = zb1 + rz1; ws[OFF_TZ2 + bh] = zb2 + rz2; }
    }
    // PASS 2: in-place exclusive prefix (same-thread RAW through L2).
    float a1 = base1, a2 = base2, az1 = zb1, az2 = zb2;
    for (int k = 0; k < 16; ++k) {
        int c = wv * 16 + k;
        float v1 = C1g[c * 64 + o]; C1g[c * 64 + o] = a1; a1 += v1;
        float v2 = C2g[c * 64 + o]; C2g[c * 64 + o] = a2; a2 += v2;
        if (o == 0) {
            float vz1 = CZ1g[c]; CZ1g[c] = az1; az1 += vz1;
            float vz2 = CZ2g[c]; CZ2g[c] = az2; az2 += vz2;
        }
    }
}

// K34: fused attention-output + gate. Block: 16 src rows x 256 cols, 8 waves.
// Phase1: wave wv owns head h=wv>>1, 8 n-rows; uniform (SGPR) row state,
// batched 8-deep remainder (chunk-8 prefix -> remainder avg ~4-6 elems).
// Phase2: gate MFMA with PRE-PACKED Hw frags (b128 loads) + fused epilogue.
// grid: b(4)*ntile(128) = 512 blocks, 512 threads.
#define FSTR 260
__global__ __launch_bounds__(512) void k34(const float* __restrict__ feat_src,
                                           const float* __restrict__ Hb,
                                           const float* __restrict__ bias,
                                           const float* __restrict__ ws,
                                           float* __restrict__ out) {
    __shared__ float FOUT[16 * FSTR];                       // 16.6KB
    __shared__ __align__(16) unsigned short Ahi[16 * 256];  // 8KB
    __shared__ __align__(16) unsigned short Alo[16 * 256];  // 8KB
    int bid = blockIdx.x;
    int b = bid >> 7, brow = (bid & 127) * 16;
    int tid = threadIdx.x;
    int o = tid & 63;
    int wv = __builtin_amdgcn_readfirstlane(tid >> 6);
    // phase 0: stage 16 feat rows as bf16 hi/lo (1024 float4)
    const float4* fb = (const float4*)(feat_src + ((size_t)b * 2048 + brow) * IND);
    #pragma unroll
    for (int it = 0; it < 2; ++it) {
        int f4 = it * 512 + tid;
        int row = f4 >> 6, c4 = f4 & 63;
        float4 v = fb[f4];
        float xs[4] = {v.x, v.y, v.z, v.w};
        uint32 hb[4], lb[4];
        #pragma unroll
        for (int j = 0; j < 4; ++j) {
            hb[j] = f32_to_bf16_rne(xs[j]);
            float hf = __uint_as_float(hb[j] << 16);
            lb[j] = f32_to_bf16_rne(xs[j] - hf);
        }
        uint2 hw, lw;
        hw.x = hb[0] | (hb[1] << 16); hw.y = hb[2] | (hb[3] << 16);
        lw.x = lb[0] | (lb[1] << 16); lw.y = lb[2] | (lb[3] << 16);
        int baddr = (row * 512 + c4 * 8) ^ ((row & 7) << 4);
        *(uint2*)((char*)Ahi + baddr) = hw;
        *(uint2*)((char*)Alo + baddr) = lw;
    }
    // phase 1: head fixed per wave; 8 rows, lane-parallel scalar prefetch
    {
        int h = wv >> 1;
        int bh = b * 4 + h;
        int nbase = (wv & 1) * 8;
        // wave-uniform hoists
        float T1v = ws[OFF_T1 + bh * 64 + o];
        float tz1 = ws[OFF_TZ1 + bh], tz2 = ws[OFF_TZ2 + bh];
        float blo = ws[OFF_MM + bh * 2], binv = ws[OFF_MM + bh * 2 + 1];
        float biasv = bias[o];
        // lane r (r = o&7) prefetches row r's scalar chain
        int r_l = o & 7;
        float t_l = ws[OFF_ASRC + bh * 2048 + brow + nbase + r_l];
        float th_l = -t_l;
        int bk = (int)floorf((th_l - blo) * binv);
        bk = bk < 0 ? 0 : (bk > NB - 1 ? NB - 1 : bk);
        const int* bst = (const int*)(ws + OFF_BST) + bh * (NB + 1);
        int jstart = bst[bk], jend = bst[bk + 1];
        int cch = (jstart + 4) >> 3; if (cch > NCH - 1) cch = NCH - 1;
        int i0c_l = cch << 3;
        int lo2_l = i0c_l < jstart ? i0c_l : jstart;
        int hi2_l = i0c_l > jend ? i0c_l : jend;
        float czp1_l = ws[OFF_CZ1 + bh * NCH + cch];
        float czp2_l = ws[OFF_CZ2 + bh * NCH + cch];
        // prefetch all 8 rows' C1/C2 prefix rows (independent 64-wide loads)
        float c1v[8], c2v[8];
        #pragma unroll
        for (int r = 0; r < 8; ++r) {
            int cch_r = __builtin_amdgcn_readfirstlane(__shfl(cch, r));
            c1v[r] = ws[OFF_C1 + ((size_t)bh * NCH + cch_r) * 64 + o];
            c2v[r] = ws[OFF_C2 + ((size_t)bh * NCH + cch_r) * 64 + o];
        }
        const float4* pk = (const float4*)(ws + OFF_PK) + (size_t)bh * 2048;
        const float* hd = ws + OFF_HDST + (size_t)bh * NDST * OUTD;
        #pragma unroll
        for (int r = 0; r < 8; ++r) {
            float t_r = __uint_as_float(
                __builtin_amdgcn_readfirstlane(__float_as_uint(__shfl(t_l, r))));
            float th = -t_r;
            int i0c = __builtin_amdgcn_readfirstlane(__shfl(i0c_l, r));
            int lo2 = __builtin_amdgcn_readfirstlane(__shfl(lo2_l, r));
            int hi2 = __builtin_amdgcn_readfirstlane(__shfl(hi2_l, r));
            float p1 = c1v[r], p2 = c2v[r];
            float zp1 = __shfl(czp1_l, r), zp2 = __shfl(czp2_l, r);
            // batched 8-deep remainder: all pk s_loads, then all hd gathers
            for (int i = lo2; i < hi2; i += 8) {
                float4 q[8];
                #pragma unroll
                for (int j = 0; j < 8; ++j) {
                    int ii = i + j < hi2 ? i + j : hi2 - 1;   // uniform (SGPR)
                    q[j] = pk[ii];
                }
                float hv[8];
                #pragma unroll
                for (int j = 0; j < 8; ++j)
                    hv[j] = hd[__float_as_int(q[j].w) + o];
                #pragma unroll
                for (int j = 0; j < 8; ++j) {
                    float sel = (q[j].x <= th ? 1.f : 0.f) - (i + j < i0c ? 1.f : 0.f);
                    sel = (i + j < hi2) ? sel : 0.f;
                    float w1 = q[j].y * sel, w2 = q[j].z * sel;
                    p1 += w1 * hv[j]; p2 += w2 * hv[j]; zp1 += w1; zp2 += w2;
                }
            }
            float et = __expf(t_r), et2 = __expf(ALPHA * t_r);
            float num = et * (T1v - p1) + et2 * p2;
            float den = et * (tz1 - zp1) + et2 * zp2;
            FOUT[(nbase + r) * FSTR + h * 64 + o] = num / den + biasv;
        }
    }
    __syncthreads();
    // phase 2: gate GEMM with pre-packed Hw frags. wave wv -> 32 cols, M=16.
    int l = tid & 63;
    int lr = l & 15, lq = l >> 4;
    int cb = wv >> 1, nb = (wv & 1) * 2;
    const uint4* gfh = (const uint4*)(ws + OFF_GFH);
    const uint4* gfl = (const uint4*)(ws + OFF_GFL);
    f32x4 acc[2];
    acc[0] = (f32x4)0.f; acc[1] = (f32x4)0.f;
    for (int ks = 0; ks < 8; ++ks) {
        bf16x8 ah, al, bh8[2], bl8[2];
        {
            int row = lr;
            int baddr = (row * 512 + ks * 64 + lq * 16) ^ ((row & 7) << 4);
            ah = *(const bf16x8*)((const char*)Ahi + baddr);
            al = *(const bf16x8*)((const char*)Alo + baddr);
        }
        #pragma unroll
        for (int ni = 0; ni < 2; ++ni) {
            int idx = ((cb * 8 + ks) * 4 + nb + ni) * 64 + l;
            uint4 th_ = gfh[idx], tl_ = gfl[idx];
            bh8[ni] = *(const bf16x8*)&th_;
            bl8[ni] = *(const bf16x8*)&tl_;
        }
        #pragma unroll
        for (int ni = 0; ni < 2; ++ni) {
            acc[ni] = __builtin_amdgcn_mfma_f32_16x16x32_bf16(ah, bh8[ni], acc[ni], 0, 0, 0);
            acc[ni] = __builtin_amdgcn_mfma_f32_16x16x32_bf16(ah, bl8[ni], acc[ni], 0, 0, 0);
            acc[ni] = __builtin_amdgcn_mfma_f32_16x16x32_bf16(al, bh8[ni], acc[ni], 0, 0, 0);
        }
    }
    // epilogue: gate + elu + mix (16 rows)
    #pragma unroll
    for (int ni = 0; ni < 2; ++ni) {
        int c = cb * 64 + (nb + ni) * 16 + lr;
        float hbv = Hb[c];
        #pragma unroll
        for (int r = 0; r < 4; ++r) {
            int rl = lq * 4 + r;
            size_t rg = (size_t)b * 2048 + brow + rl;
            float x = acc[ni][r] + hbv;
            float g = 1.f / (1.f + __expf(-x));
            float fo = FOUT[rl * FSTR + c];
            float e = fo > 0.f ? fo : expm1f(fo);
            float fs = feat_src[rg * 256 + c];
            out[rg * 256 + c] = g * e + (1.f - g) * fs;
        }
    }
}

extern "C" void kernel_launch(void* const* d_in, const int* in_sizes, int n_in,
                              void* d_out, int out_size, void* d_ws, size_t ws_size,
                              hipStream_t stream) {
    const float* feat_src = (const float*)d_in[0];
    const float* feat_dst = (const float*)d_in[1];
    const float* W        = (const float*)d_in[2];
    const float* bias     = (const float*)d_in[3];
    const float* w_src    = (const float*)d_in[4];
    const float* w_dst    = (const float*)d_in[5];
    const float* Hw       = (const float*)d_in[6];
    const float* Hb       = (const float*)d_in[7];
    float* out = (float*)d_out;
    float* ws  = (float*)d_ws;

    k1_mfma<<<512, 256, 0, stream>>>(feat_src, feat_dst, W, w_src, w_dst, ws);
    kmid<<<24, 1024, 0, stream>>>(Hw, ws);
    k34<<<512, 512, 0, stream>>>(feat_src, Hb, bias, ws, out);
}

// Round 13
// 65.923 us; speedup vs baseline: 161.0653x; 1.0138x over previous
//
#include <hip/hip_runtime.h>
#include <math.h>

typedef unsigned int uint32;
typedef __attribute__((ext_vector_type(8))) short bf16x8;
typedef __attribute__((ext_vector_type(4))) float f32x4;

#define BB 4
#define HH 4
#define NSRC 2048
#define NDST 2048
#define IND 256
#define OUTD 64
#define ALPHA 0.2f
#define NB 2048           // value buckets per (b,h)
#define NCH 256           // 8-element chunks per (b,h)

// workspace layout (float offsets)
#define OFF_HDST   0            // 2097152
#define OFF_ASRC   2097152      // 32768
#define OFF_ADST   2129920      // 32768
#define OFF_PK     2162688      // 131072 (float4 {d, w1, w2, idx*64})
#define OFF_C1     2293760      // 262144 (chunk-8 prefix, exclusive)
#define OFF_C2     2555904      // 262144
#define OFF_CZ1    2818048      // 4096
#define OFF_CZ2    2822144      // 4096
#define OFF_T1     2826240      // 1024
#define OFF_TZ1    2827264      // 16
#define OFF_TZ2    2827280      // 16
#define OFF_BST    2827296      // 16*2049 ints
#define OFF_MM     2860080      // 16*2 (lo, inv)
#define OFF_GFH    2860112      // 32768 (Hw^T frags hi, 65536 bf16)
#define OFF_GFL    2892880      // 32768

__device__ __forceinline__ float fast_tanh(float x) {
    float e = __expf(2.f * x);
    return 1.f - 2.f / (e + 1.f);
}

__device__ __forceinline__ uint32 f32_to_bf16_rne(float x) {
    uint32 u = __float_as_uint(x);
    return (u + 0x7fffu + ((u >> 16) & 1u)) >> 16;
}

// split 8 f32 into bf16 hi/lo packed fragments
__device__ __forceinline__ void split8(const float* x, bf16x8& h8, bf16x8& l8) {
    uint32 hw[4], lw[4];
    #pragma unroll
    for (int p = 0; p < 4; ++p) {
        uint32 h0 = f32_to_bf16_rne(x[2 * p]);
        float f0 = __uint_as_float(h0 << 16);
        uint32 l0 = f32_to_bf16_rne(x[2 * p] - f0);
        uint32 h1 = f32_to_bf16_rne(x[2 * p + 1]);
        float f1 = __uint_as_float(h1 << 16);
        uint32 l1 = f32_to_bf16_rne(x[2 * p + 1] - f1);
        hw[p] = h0 | (h1 << 16);
        lw[p] = l0 | (l1 << 16);
    }
    h8 = *(bf16x8*)hw; l8 = *(bf16x8*)lw;
}

// K1: projection via MFMA, split-bf16 3-pass. Block: 32 rows x 4 heads
// (wave w = head w). W fragments gathered per-lane from global (L2-resident).
// grid: s(2)*b(4)*t(64) = 512 blocks, 256 threads.
__global__ __launch_bounds__(256) void k1_mfma(const float* __restrict__ feat_src,
                                               const float* __restrict__ feat_dst,
                                               const float* __restrict__ W,
                                               const float* __restrict__ w_src,
                                               const float* __restrict__ w_dst,
                                               float* __restrict__ ws) {
    __shared__ __align__(16) unsigned short Ahi[32 * 256];   // 16KB
    __shared__ __align__(16) unsigned short Alo[32 * 256];   // 16KB
    int bid = blockIdx.x;
    int t = bid & 63, b = (bid >> 6) & 3, s = bid >> 8;
    int tid = threadIdx.x;
    const float* feat = s ? feat_dst : feat_src;
    const float4* fb = (const float4*)(feat + ((size_t)b * 2048 + t * 32) * IND);
    // stage feat tile -> bf16 hi/lo LDS, XOR swizzle (byte ^= (row&7)<<4)
    #pragma unroll
    for (int it = 0; it < 8; ++it) {
        int f4 = it * 256 + tid;
        int row = f4 >> 6, c4 = f4 & 63;
        float4 v = fb[f4];
        float xs[4] = {v.x, v.y, v.z, v.w};
        uint32 hb[4], lb[4];
        #pragma unroll
        for (int j = 0; j < 4; ++j) {
            hb[j] = f32_to_bf16_rne(xs[j]);
            float hf = __uint_as_float(hb[j] << 16);
            lb[j] = f32_to_bf16_rne(xs[j] - hf);
        }
        uint2 hw, lw;
        hw.x = hb[0] | (hb[1] << 16); hw.y = hb[2] | (hb[3] << 16);
        lw.x = lb[0] | (lb[1] << 16); lw.y = lb[2] | (lb[3] << 16);
        int baddr = (row * 512 + c4 * 8) ^ ((row & 7) << 4);
        *(uint2*)((char*)Ahi + baddr) = hw;
        *(uint2*)((char*)Alo + baddr) = lw;
    }
    __syncthreads();
    int w = tid >> 6, l = tid & 63;
    int lr = l & 15, lq = l >> 4;
    const float* Wh = W + (size_t)w * 16384;
    f32x4 acc[2][4];
    #pragma unroll
    for (int mi = 0; mi < 2; ++mi)
        #pragma unroll
        for (int ni = 0; ni < 4; ++ni) acc[mi][ni] = (f32x4)0.f;
    for (int ks = 0; ks < 8; ++ks) {
        bf16x8 ah[2], al[2], bh8[4], bl8[4];
        #pragma unroll
        for (int mi = 0; mi < 2; ++mi) {
            int row = mi * 16 + lr;
            int baddr = (row * 512 + ks * 64 + lq * 16) ^ ((row & 7) << 4);
            ah[mi] = *(const bf16x8*)((const char*)Ahi + baddr);
            al[mi] = *(const bf16x8*)((const char*)Alo + baddr);
        }
        int kb = ks * 32 + lq * 8;
        #pragma unroll
        for (int ni = 0; ni < 4; ++ni) {
            const float* wp = Wh + (size_t)kb * 64 + ni * 16 + lr;
            float xv[8];
            #pragma unroll
            for (int j = 0; j < 8; ++j) xv[j] = wp[j * 64];
            split8(xv, bh8[ni], bl8[ni]);
        }
        #pragma unroll
        for (int mi = 0; mi < 2; ++mi)
            #pragma unroll
            for (int ni = 0; ni < 4; ++ni) {
                acc[mi][ni] = __builtin_amdgcn_mfma_f32_16x16x32_bf16(ah[mi], bh8[ni], acc[mi][ni], 0, 0, 0);
                acc[mi][ni] = __builtin_amdgcn_mfma_f32_16x16x32_bf16(ah[mi], bl8[ni], acc[mi][ni], 0, 0, 0);
                acc[mi][ni] = __builtin_amdgcn_mfma_f32_16x16x32_bf16(al[mi], bh8[ni], acc[mi][ni], 0, 0, 0);
            }
    }
    if (s) {
        float* hd = ws + OFF_HDST + ((size_t)(b * HH + w) * NDST + t * 32) * OUTD;
        #pragma unroll
        for (int mi = 0; mi < 2; ++mi)
            #pragma unroll
            for (int ni = 0; ni < 4; ++ni)
                #pragma unroll
                for (int r = 0; r < 4; ++r)
                    hd[(mi * 16 + lq * 4 + r) * 64 + ni * 16 + lr] = acc[mi][ni][r];
    }
    const float* wa = (s ? w_dst : w_src) + w * OUTD;
    float wa_v[4];
    #pragma unroll
    for (int ni = 0; ni < 4; ++ni) wa_v[ni] = wa[ni * 16 + lr];
    float* ap = ws + (s ? OFF_ADST : OFF_ASRC) + (b * HH + w) * NSRC + t * 32;
    #pragma unroll
    for (int mi = 0; mi < 2; ++mi)
        #pragma unroll
        for (int r = 0; r < 4; ++r) {
            float p = 0.f;
            #pragma unroll
            for (int ni = 0; ni < 4; ++ni) p += fast_tanh(acc[mi][ni][r]) * wa_v[ni];
            p += __shfl_xor(p, 1); p += __shfl_xor(p, 2);
            p += __shfl_xor(p, 4); p += __shfl_xor(p, 8);
            if (lr == 0) ap[mi * 16 + lq * 4 + r] = p;
        }
}

// KMID: blocks 0..15: per (b,h) bucket permutation + chunk-8 sums +
// two-pass register-light prefix (no VGPR arrays -> no scratch spill at
// 1024thr/64-VGPR cap). Blocks 16..23: pack Hw^T into MFMA B-frag order.
// grid: 24 blocks, 1024 threads.
__global__ __launch_bounds__(1024) void kmid(const float* __restrict__ Hw,
                                             float* __restrict__ ws) {
    if (blockIdx.x >= 16) {
        // Hw^T fragment packing: 8192 lane-slots, one per thread.
        int g = (blockIdx.x - 16) * 1024 + threadIdx.x;   // 0..8191
        int l = g & 63, ni = (g >> 6) & 3, ks = (g >> 8) & 7, cb = g >> 11;
        int col = cb * 64 + ni * 16 + (l & 15);
        int k0 = ks * 32 + (l >> 4) * 8;
        unsigned short hs[8], lsv[8];
        #pragma unroll
        for (int j = 0; j < 8; ++j) {
            float w = Hw[(size_t)col * 256 + k0 + j];
            uint32 hb = f32_to_bf16_rne(w);
            float hf = __uint_as_float(hb << 16);
            uint32 lb = f32_to_bf16_rne(w - hf);
            hs[j] = (unsigned short)hb; lsv[j] = (unsigned short)lb;
        }
        unsigned short* fh = (unsigned short*)(ws + OFF_GFH);
        unsigned short* fl = (unsigned short*)(ws + OFF_GFL);
        int slab = ((cb * 8 + ks) * 4 + ni) * 512 + l * 8;
        #pragma unroll
        for (int j = 0; j < 8; ++j) { fh[slab + j] = hs[j]; fl[slab + j] = lsv[j]; }
        return;
    }
    __shared__ int   hist[2048];      // counts -> reused as scatter cursors
    __shared__ float keysP[2048];
    __shared__ int   idxP[2048];
    __shared__ float w1L[2048];
    __shared__ float w2L[2048];
    __shared__ float ST1[16 * 64], ST2[16 * 64];
    __shared__ float SZ1[16], SZ2[16];
    __shared__ float red[32];
    __shared__ float loinv[2];
    __shared__ int wtot[16];
    int bh = blockIdx.x, tid = threadIdx.x;
    int lane = tid & 63, wv = tid >> 6;
    const float* ad = ws + OFF_ADST + bh * NDST;
    float d0 = ad[tid], d1 = ad[tid + 1024];
    float mn = fminf(d0, d1), mx = fmaxf(d0, d1);
    #pragma unroll
    for (int off = 32; off; off >>= 1) {
        mn = fminf(mn, __shfl_xor(mn, off));
        mx = fmaxf(mx, __shfl_xor(mx, off));
    }
    if (lane == 0) { red[wv] = mn; red[16 + wv] = mx; }
    hist[tid] = 0; hist[tid + 1024] = 0;
    __syncthreads();
    if (tid == 0) {
        float lo = red[0], hi = red[16];
        #pragma unroll
        for (int i = 1; i < 16; ++i) { lo = fminf(lo, red[i]); hi = fmaxf(hi, red[16 + i]); }
        float wd = hi - lo;
        float inv = (float)NB / (wd + wd * 1e-6f + 1e-30f);
        loinv[0] = lo; loinv[1] = inv;
        ws[OFF_MM + bh * 2] = lo; ws[OFF_MM + bh * 2 + 1] = inv;
    }
    __syncthreads();
    float lo = loinv[0], inv = loinv[1];
    int b0 = (int)((d0 - lo) * inv); b0 = b0 < 0 ? 0 : (b0 > NB - 1 ? NB - 1 : b0);
    int b1 = (int)((d1 - lo) * inv); b1 = b1 < 0 ? 0 : (b1 > NB - 1 ? NB - 1 : b1);
    atomicAdd(&hist[b0], 1);
    atomicAdd(&hist[b1], 1);
    __syncthreads();
    int h0 = hist[2 * tid], h1 = hist[2 * tid + 1];
    int s = h0 + h1, sc = s;
    #pragma unroll
    for (int off = 1; off < 64; off <<= 1) {
        int v = __shfl_up(sc, off);
        if (lane >= off) sc += v;
    }
    if (lane == 63) wtot[wv] = sc;
    __syncthreads();
    if (tid == 0) {
        int r = 0;
        #pragma unroll
        for (int i = 0; i < 16; ++i) { int v = wtot[i]; wtot[i] = r; r += v; }
    }
    __syncthreads();
    int base = wtot[wv] + (sc - s);
    int* bstg = (int*)(ws + OFF_BST) + bh * (NB + 1);
    hist[2 * tid] = base;
    hist[2 * tid + 1] = base + h0;
    bstg[2 * tid] = base;
    bstg[2 * tid + 1] = base + h0;
    if (tid == 0) bstg[NB] = NDST;
    __syncthreads();
    int p0 = atomicAdd(&hist[b0], 1);
    keysP[p0] = d0; idxP[p0] = tid;
    w1L[p0] = __expf(d0); w2L[p0] = __expf(ALPHA * d0);
    int p1 = atomicAdd(&hist[b1], 1);
    keysP[p1] = d1; idxP[p1] = tid + 1024;
    w1L[p1] = __expf(d1); w2L[p1] = __expf(ALPHA * d1);
    __syncthreads();
    // packed PK dump: {d, w1, w2, idx*64 (int bits)}
    {
        float4* pkg = (float4*)(ws + OFF_PK) + (size_t)bh * 2048;
        pkg[tid] = make_float4(keysP[tid], w1L[tid], w2L[tid],
                               __int_as_float(idxP[tid] * 64));
        pkg[tid + 1024] = make_float4(keysP[tid + 1024], w1L[tid + 1024], w2L[tid + 1024],
                                      __int_as_float(idxP[tid + 1024] * 64));
    }
    // chunk-8 sums: wave wv owns chunks wv*16..wv*16+16, lane = o.
    // PASS 1: raw sums -> global, only scalar running totals in regs.
    const float* hd = ws + OFF_HDST + (size_t)bh * NDST * OUTD;
    float* C1g = ws + OFF_C1 + (size_t)bh * NCH * 64;
    float* C2g = ws + OFF_C2 + (size_t)bh * NCH * 64;
    float* CZ1g = ws + OFF_CZ1 + bh * NCH;
    float* CZ2g = ws + OFF_CZ2 + bh * NCH;
    int o = lane;
    float run1 = 0.f, run2 = 0.f, rz1 = 0.f, rz2 = 0.f;
    for (int k = 0; k < 16; ++k) {
        int c = wv * 16 + k;
        float c1 = 0.f, c2 = 0.f, cz1 = 0.f, cz2 = 0.f;
        #pragma unroll
        for (int ii = 0; ii < 8; ++ii) {
            int i = c * 8 + ii;
            int m = idxP[i];
            float w1 = w1L[i], w2 = w2L[i];
            float hv = hd[m * 64 + o];
            c1 += w1 * hv; c2 += w2 * hv; cz1 += w1; cz2 += w2;
        }
        C1g[c * 64 + o] = c1; C2g[c * 64 + o] = c2;         // raw
        if (o == 0) { CZ1g[c] = cz1; CZ2g[c] = cz2; }       // raw
        run1 += c1; run2 += c2; rz1 += cz1; rz2 += cz2;
    }
    ST1[wv * 64 + o] = run1; ST2[wv * 64 + o] = run2;
    if (lane == 0) { SZ1[wv] = rz1; SZ2[wv] = rz2; }
    __syncthreads();
    float base1 = 0.f, base2 = 0.f, zb1 = 0.f, zb2 = 0.f;
    for (int ss = 0; ss < wv; ++ss) {
        base1 += ST1[ss * 64 + o]; base2 += ST2[ss * 64 + o];
        zb1 += SZ1[ss];            zb2 += SZ2[ss];
    }
    if (wv == 15) {
        ws[OFF_T1 + bh * 64 + o] = base1 + run1;
        if (o == 0) { ws[OFF_TZ1 + bh] = zb1 + rz1; ws[OFF_TZ2 + bh] = zb2 + rz2; }
    }
    // PASS 2: in-place exclusive prefix (same-thread RAW through L2).
    float a1 = base1, a2 = base2, az1 = zb1, az2 = zb2;
    for (int k = 0; k < 16; ++k) {
        int c = wv * 16 + k;
        float v1 = C1g[c * 64 + o]; C1g[c * 64 + o] = a1; a1 += v1;
        float v2 = C2g[c * 64 + o]; C2g[c * 64 + o] = a2; a2 += v2;
        if (o == 0) {
            float vz1 = CZ1g[c]; CZ1g[c] = az1; az1 += vz1;
            float vz2 = CZ2g[c]; CZ2g[c] = az2; az2 += vz2;
        }
    }
}

// K34: fused attention-output + gate. Block: 16 src rows x 256 cols, 8 waves.
// XCD-aware decode (T1): xcd = bid&7 owns batch b = xcd>>1, so each XCD's L2
// caches only one b's HDST/PK/C structures (~3MB < 4MB) instead of all four.
// Phase1: wave wv owns head h=wv>>1, 8 n-rows; uniform (SGPR) row state,
// batched 8-deep remainder. Phase2: gate MFMA with pre-packed Hw frags.
// grid: 512 blocks, 512 threads.
#define FSTR 260
__global__ __launch_bounds__(512) void k34(const float* __restrict__ feat_src,
                                           const float* __restrict__ Hb,
                                           const float* __restrict__ bias,
                                           const float* __restrict__ ws,
                                           float* __restrict__ out) {
    __shared__ float FOUT[16 * FSTR];                       // 16.6KB
    __shared__ __align__(16) unsigned short Ahi[16 * 256];  // 8KB
    __shared__ __align__(16) unsigned short Alo[16 * 256];  // 8KB
    int bid = blockIdx.x;
    // XCD-locality decode: b = (bid&7)>>1; tile = (bid&1)*64 + (bid>>3)
    int b = (bid & 7) >> 1;
    int brow = (((bid & 1) << 6) | (bid >> 3)) * 16;
    int tid = threadIdx.x;
    int o = tid & 63;
    int wv = __builtin_amdgcn_readfirstlane(tid >> 6);
    // phase 0: stage 16 feat rows as bf16 hi/lo (1024 float4)
    const float4* fb = (const float4*)(feat_src + ((size_t)b * 2048 + brow) * IND);
    #pragma unroll
    for (int it = 0; it < 2; ++it) {
        int f4 = it * 512 + tid;
        int row = f4 >> 6, c4 = f4 & 63;
        float4 v = fb[f4];
        float xs[4] = {v.x, v.y, v.z, v.w};
        uint32 hb[4], lb[4];
        #pragma unroll
        for (int j = 0; j < 4; ++j) {
            hb[j] = f32_to_bf16_rne(xs[j]);
            float hf = __uint_as_float(hb[j] << 16);
            lb[j] = f32_to_bf16_rne(xs[j] - hf);
        }
        uint2 hw, lw;
        hw.x = hb[0] | (hb[1] << 16); hw.y = hb[2] | (hb[3] << 16);
        lw.x = lb[0] | (lb[1] << 16); lw.y = lb[2] | (lb[3] << 16);
        int baddr = (row * 512 + c4 * 8) ^ ((row & 7) << 4);
        *(uint2*)((char*)Ahi + baddr) = hw;
        *(uint2*)((char*)Alo + baddr) = lw;
    }
    // phase 1: head fixed per wave; 8 rows, lane-parallel scalar prefetch
    {
        int h = wv >> 1;
        int bh = b * 4 + h;
        int nbase = (wv & 1) * 8;
        // wave-uniform hoists
        float T1v = ws[OFF_T1 + bh * 64 + o];
        float tz1 = ws[OFF_TZ1 + bh], tz2 = ws[OFF_TZ2 + bh];
        float blo = ws[OFF_MM + bh * 2], binv = ws[OFF_MM + bh * 2 + 1];
        float biasv = bias[o];
        // lane r (r = o&7) prefetches row r's scalar chain
        int r_l = o & 7;
        float t_l = ws[OFF_ASRC + bh * 2048 + brow + nbase + r_l];
        float th_l = -t_l;
        int bk = (int)floorf((th_l - blo) * binv);
        bk = bk < 0 ? 0 : (bk > NB - 1 ? NB - 1 : bk);
        const int* bst = (const int*)(ws + OFF_BST) + bh * (NB + 1);
        int jstart = bst[bk], jend = bst[bk + 1];
        int cch = (jstart + 4) >> 3; if (cch > NCH - 1) cch = NCH - 1;
        int i0c_l = cch << 3;
        int lo2_l = i0c_l < jstart ? i0c_l : jstart;
        int hi2_l = i0c_l > jend ? i0c_l : jend;
        float czp1_l = ws[OFF_CZ1 + bh * NCH + cch];
        float czp2_l = ws[OFF_CZ2 + bh * NCH + cch];
        // prefetch all 8 rows' C1/C2 prefix rows (independent 64-wide loads)
        float c1v[8], c2v[8];
        #pragma unroll
        for (int r = 0; r < 8; ++r) {
            int cch_r = __builtin_amdgcn_readfirstlane(__shfl(cch, r));
            c1v[r] = ws[OFF_C1 + ((size_t)bh * NCH + cch_r) * 64 + o];
            c2v[r] = ws[OFF_C2 + ((size_t)bh * NCH + cch_r) * 64 + o];
        }
        const float4* pk = (const float4*)(ws + OFF_PK) + (size_t)bh * 2048;
        const float* hd = ws + OFF_HDST + (size_t)bh * NDST * OUTD;
        #pragma unroll
        for (int r = 0; r < 8; ++r) {
            float t_r = __uint_as_float(
                __builtin_amdgcn_readfirstlane(__float_as_uint(__shfl(t_l, r))));
            float th = -t_r;
            int i0c = __builtin_amdgcn_readfirstlane(__shfl(i0c_l, r));
            int lo2 = __builtin_amdgcn_readfirstlane(__shfl(lo2_l, r));
            int hi2 = __builtin_amdgcn_readfirstlane(__shfl(hi2_l, r));
            float p1 = c1v[r], p2 = c2v[r];
            float zp1 = __shfl(czp1_l, r), zp2 = __shfl(czp2_l, r);
            // batched 8-deep remainder: all pk s_loads, then all hd gathers
            for (int i = lo2; i < hi2; i += 8) {
                float4 q[8];
                #pragma unroll
                for (int j = 0; j < 8; ++j) {
                    int ii = i + j < hi2 ? i + j : hi2 - 1;   // uniform (SGPR)
                    q[j] = pk[ii];
                }
                float hv[8];
                #pragma unroll
                for (int j = 0; j < 8; ++j)
                    hv[j] = hd[__float_as_int(q[j].w) + o];
                #pragma unroll
                for (int j = 0; j < 8; ++j) {
                    float sel = (q[j].x <= th ? 1.f : 0.f) - (i + j < i0c ? 1.f : 0.f);
                    sel = (i + j < hi2) ? sel : 0.f;
                    float w1 = q[j].y * sel, w2 = q[j].z * sel;
                    p1 += w1 * hv[j]; p2 += w2 * hv[j]; zp1 += w1; zp2 += w2;
                }
            }
            float et = __expf(t_r), et2 = __expf(ALPHA * t_r);
            float num = et * (T1v - p1) + et2 * p2;
            float den = et * (tz1 - zp1) + et2 * zp2;
            FOUT[(nbase + r) * FSTR + h * 64 + o] = num / den + biasv;
        }
    }
    __syncthreads();
    // phase 2: gate GEMM with pre-packed Hw frags. wave wv -> 32 cols, M=16.
    int l = tid & 63;
    int lr = l & 15, lq = l >> 4;
    int cb = wv >> 1, nb = (wv & 1) * 2;
    const uint4* gfh = (const uint4*)(ws + OFF_GFH);
    const uint4* gfl = (const uint4*)(ws + OFF_GFL);
    f32x4 acc[2];
    acc[0] = (f32x4)0.f; acc[1] = (f32x4)0.f;
    for (int ks = 0; ks < 8; ++ks) {
        bf16x8 ah, al, bh8[2], bl8[2];
        {
            int row = lr;
            int baddr = (row * 512 + ks * 64 + lq * 16) ^ ((row & 7) << 4);
            ah = *(const bf16x8*)((const char*)Ahi + baddr);
            al = *(const bf16x8*)((const char*)Alo + baddr);
        }
        #pragma unroll
        for (int ni = 0; ni < 2; ++ni) {
            int idx = ((cb * 8 + ks) * 4 + nb + ni) * 64 + l;
            uint4 th_ = gfh[idx], tl_ = gfl[idx];
            bh8[ni] = *(const bf16x8*)&th_;
            bl8[ni] = *(const bf16x8*)&tl_;
        }
        #pragma unroll
        for (int ni = 0; ni < 2; ++ni) {
            acc[ni] = __builtin_amdgcn_mfma_f32_16x16x32_bf16(ah, bh8[ni], acc[ni], 0, 0, 0);
            acc[ni] = __builtin_amdgcn_mfma_f32_16x16x32_bf16(ah, bl8[ni], acc[ni], 0, 0, 0);
            acc[ni] = __builtin_amdgcn_mfma_f32_16x16x32_bf16(al, bh8[ni], acc[ni], 0, 0, 0);
        }
    }
    // epilogue: gate + elu + mix (16 rows)
    #pragma unroll
    for (int ni = 0; ni < 2; ++ni) {
        int c = cb * 64 + (nb + ni) * 16 + lr;
        float hbv = Hb[c];
        #pragma unroll
        for (int r = 0; r < 4; ++r) {
            int rl = lq * 4 + r;
            size_t rg = (size_t)b * 2048 + brow + rl;
            float x = acc[ni][r] + hbv;
            float g = 1.f / (1.f + __expf(-x));
            float fo = FOUT[rl * FSTR + c];
            float e = fo > 0.f ? fo : expm1f(fo);
            float fs = feat_src[rg * 256 + c];
            out[rg * 256 + c] = g * e + (1.f - g) * fs;
        }
    }
}

extern "C" void kernel_launch(void* const* d_in, const int* in_sizes, int n_in,
                              void* d_out, int out_size, void* d_ws, size_t ws_size,
                              hipStream_t stream) {
    const float* feat_src = (const float*)d_in[0];
    const float* feat_dst = (const float*)d_in[1];
    const float* W        = (const float*)d_in[2];
    const float* bias     = (const float*)d_in[3];
    const float* w_src    = (const float*)d_in[4];
    const float* w_dst    = (const float*)d_in[5];
    const float* Hw       = (const float*)d_in[6];
    const float* Hb       = (const float*)d_in[7];
    float* out = (float*)d_out;
    float* ws  = (float*)d_ws;

    k1_mfma<<<512, 256, 0, stream>>>(feat_src, feat_dst, W, w_src, w_dst, ws);
    kmid<<<24, 1024, 0, stream>>>(Hw, ws);
    k34<<<512, 512, 0, stream>>>(feat_src, Hb, bias, ws, out);
}